// Round 9
// baseline (374.412 us; speedup 1.0000x reference)
//
#include <hip/hip_runtime.h>
#include <hip/hip_bf16.h>

// Problem constants
#define BB 256
#define PP 20
#define HH 4
#define FF 1024
#define LL 300
#define LLP 320           // LL padded to 32-multiple
#define DCAT 1344         // FF + LLP
#define SS 16
#define HDIM 1024
#define CC 117
#define NNODE (BB * PP)              // 5120
#define NREAD (BB * (PP * HH - HH))  // 19456
#define EPB 8
#define TK 32

typedef __attribute__((ext_vector_type(8))) short bf16x8v;
typedef __attribute__((ext_vector_type(4))) float f32x4v;
typedef __attribute__((ext_vector_type(4))) unsigned short u16x4;

__device__ __forceinline__ float bf2f(unsigned short u) {
  return __uint_as_float((unsigned int)u << 16);
}
__device__ __forceinline__ unsigned short f2b(float f) {
  __hip_bfloat16 h = __float2bfloat16(f);
  return *(unsigned short*)&h;
}

// ---------------------------------------------------------------------------
// Dtype sniff (flag[0]=1 -> inputs are fp32).
// ---------------------------------------------------------------------------
__global__ void sniff_dtype(const unsigned short* __restrict__ buf,
                            int* __restrict__ flag) {
  int t = threadIdx.x;
  int votes = 0;
  for (int i = t; i < 512; i += 256) {
    unsigned int u = (unsigned int)buf[i] << 16;
    float v = __uint_as_float(u);
    float a = fabsf(v);
    if (v == v && a > 9.3e-10f && a < 1.1e9f) votes++;
  }
  __shared__ int sv[256];
  sv[t] = votes;
  __syncthreads();
  for (int s = 128; s > 0; s >>= 1) {
    if (t < s) sv[t] += sv[t + s];
    __syncthreads();
  }
  if (t == 0) flag[0] = (sv[0] < 448) ? 1 : 0;
}

// ---------------------------------------------------------------------------
// prep_all: ONE launch for every conversion/transpose (unchanged, Round 8).
// ---------------------------------------------------------------------------
#define NB_FEAT 5120
#define NB_W2V 1600
#define NB_SM 79
#define PREP_BLOCKS 10739

__global__ __launch_bounds__(256) void prep_all(
    const void* __restrict__ s0, const void* __restrict__ s1,
    const void* __restrict__ s3, const void* __restrict__ s4,
    const void* __restrict__ s5, const void* __restrict__ s6,
    const void* __restrict__ s7, const void* __restrict__ s8,
    const void* __restrict__ s9, const void* __restrict__ s10,
    __hip_bfloat16* __restrict__ xcat, __hip_bfloat16* __restrict__ cAv,
    __hip_bfloat16* __restrict__ cAl, __hip_bfloat16* __restrict__ cB1,
    __hip_bfloat16* __restrict__ cB2, __hip_bfloat16* __restrict__ cW1sp,
    __hip_bfloat16* __restrict__ dWvT, __hip_bfloat16* __restrict__ dWlT,
    __hip_bfloat16* __restrict__ dW1d, __hip_bfloat16* __restrict__ dW1s,
    __hip_bfloat16* __restrict__ dW2T, const int* __restrict__ flag) {
  const int bid = blockIdx.x;
  const int t = threadIdx.x;
  const int fl = flag[0];

  if (bid < NB_FEAT) {
    long i = (long)bid * 256 + t;
    int r = (int)(i >> 8);
    int c = ((int)i & 255) * 4;
    u16x4 o;
    if (fl) {
      float4 v = *(const float4*)((const float*)s0 + (long)r * FF + c);
      o[0] = f2b(v.x); o[1] = f2b(v.y); o[2] = f2b(v.z); o[3] = f2b(v.w);
    } else {
      o = *(const u16x4*)((const __hip_bfloat16*)s0 + (long)r * FF + c);
    }
    *(u16x4*)(xcat + (long)r * DCAT + c) = o;
  } else if (bid < NB_FEAT + NB_W2V) {
    long i = (long)(bid - NB_FEAT) * 256 + t;
    int r = (int)(i / 80), c = ((int)(i % 80)) * 4;
    u16x4 o;
    if (c + 4 <= LL) {
      if (fl) {
        const float* p = (const float*)s1 + (long)r * LL + c;
        o[0] = f2b(p[0]); o[1] = f2b(p[1]); o[2] = f2b(p[2]); o[3] = f2b(p[3]);
      } else {
        const __hip_bfloat16* p = (const __hip_bfloat16*)s1 + (long)r * LL + c;
        o[0] = *(const unsigned short*)(p + 0);
        o[1] = *(const unsigned short*)(p + 1);
        o[2] = *(const unsigned short*)(p + 2);
        o[3] = *(const unsigned short*)(p + 3);
      }
    } else {
#pragma unroll
      for (int j = 0; j < 4; j++) {
        float v = 0.f;
        if (c + j < LL)
          v = fl ? ((const float*)s1)[(long)r * LL + c + j]
                 : __bfloat162float(
                       ((const __hip_bfloat16*)s1)[(long)r * LL + c + j]);
        o[j] = f2b(v);
      }
    }
    *(u16x4*)(xcat + (long)r * DCAT + FF + c) = o;
  } else if (bid < NB_FEAT + NB_W2V + NB_SM) {
    int i = (bid - NB_FEAT - NB_W2V) * 256 + t;
    auto rd = [&](const void* p, long idx) -> float {
      return fl ? ((const float*)p)[idx]
                : __bfloat162float(((const __hip_bfloat16*)p)[idx]);
    };
    if (i < 2048) cAv[i] = __float2bfloat16(rd(s4, i));
    else if (i < 2648) cAl[i - 2048] = __float2bfloat16(rd(s6, i - 2048));
    else if (i < 3672) cB1[i - 2648] = __float2bfloat16(rd(s8, i - 2648));
    else if (i < 3789) cB2[i - 3672] = __float2bfloat16(rd(s10, i - 3672));
    else if (i < 20173)
      cW1sp[i - 3789] = __float2bfloat16(rd(s7, 1355776L + (i - 3789)));
  } else {
    int idx = bid - (NB_FEAT + NB_W2V + NB_SM);
    const int OFFS[8] = {0, 1024, 1124, 2148, 2468, 3492, 3812, 3940};
    const int NKB[7] = {32, 10, 32, 10, 32, 10, 32};
    const int ROW0[7] = {0, 0, 0, 1024, 1640, 1340, 0};
    const int KK[7] = {1024, 300, 1024, 300, 1024, 300, 1024};
    const int NN[7] = {1024, 300, 1024, 1024, 1024, 1024, 117};
    const int LD[7] = {1024, 300, 1024, 1024, 1024, 1024, 117};
    const int KP[7] = {1024, 320, 1024, 320, 1024, 320, 1024};
    const int KOFF[7] = {0, 0, 0, 1024, 0, 1024, 0};
    const int KLD[7] = {1024, 320, DCAT, DCAT, DCAT, DCAT, 1024};
    int z = 0;
    while (z < 6 && idx >= OFFS[z + 1]) z++;
    idx -= OFFS[z];
    const int kb = (idx % NKB[z]) * 32, nb = (idx / NKB[z]) * 32;
    const void* src = (z == 0) ? s3 : (z == 1) ? s5 : (z == 6) ? s9 : s7;
    __hip_bfloat16* dst = (z == 0) ? dWvT : (z == 1) ? dWlT
                          : (z <= 3) ? dW1d : (z <= 5) ? dW1s : dW2T;
    const int row0 = ROW0[z], K = KK[z], N = NN[z], ld = LD[z], Kp = KP[z];
    const int koff = KOFF[z], kld = KLD[z];
    __shared__ float tile[32][33];
    const int tx = t & 31, ty = t >> 5;
    for (int i = ty; i < 32; i += 8) {
      int k = kb + i, n = nb + tx;
      float v = 0.f;
      if (k < K && n < N) {
        long sidx = (long)(row0 + k) * ld + n;
        v = fl ? ((const float*)src)[sidx]
               : __bfloat162float(((const __hip_bfloat16*)src)[sidx]);
      }
      tile[i][tx] = v;
    }
    __syncthreads();
    for (int i = ty; i < 32; i += 8) {
      int n = nb + i, k = kb + tx;
      if (n < N && k < Kp)
        dst[(long)n * kld + koff + k] = __float2bfloat16(tile[tx][i]);
    }
  }
}

// ---------------------------------------------------------------------------
// DIRECT-LOAD MFMA GEMM: no LDS, no barriers. Fragments for 16x16x32 bf16
// are per-lane 16B contiguous row slices of A[M,K] / BT[N,K] — loaded
// straight global->VGPR (matrices are L2-resident at these shapes; L1
// absorbs intra-block duplicates). 1-deep register pipeline: fragments for
// k+1 are issued before the MFMAs of k, so the compiler emits fine-grained
// s_waitcnt vmcnt(N) interleave (the AITER pattern) instead of the staged
// structure's vmcnt(0) barrier drain.
// ---------------------------------------------------------------------------
struct GDesc {
  const __hip_bfloat16* A;
  const __hip_bfloat16* BT;
  void* C;
  const __hip_bfloat16* bias;
  int M, N, K, lda, ldbt, ldc;
  int row_mode, do_relu, c_mode, nbx, nby;
};

template <int BM, int BN, int WR, int WC>
__global__ __launch_bounds__(256) void gemm_direct(GDesc d0, GDesc d1,
                                                   const int* outflag) {
  constexpr int MI = BM / WR / 16;
  constexpr int NI = BN / WC / 16;
  const GDesc d = blockIdx.z ? d1 : d0;
  if ((int)blockIdx.x >= d.nbx || (int)blockIdx.y >= d.nby) return;
  const int tid = threadIdx.x;
  const int lane = tid & 63;
  const int wave = tid >> 6;
  const int wm = (wave % WR) * (BM / WR);
  const int wn = (wave / WR) * (BN / WC);
  const int m0 = blockIdx.y * BM;
  const int n0 = blockIdx.x * BN;
  const int col_l = lane & 15;
  const int quad = lane >> 4;
  const int M = d.M, N = d.N;

  // Per-lane row base pointers (k advances via offset).
  const __hip_bfloat16* pA[MI];
#pragma unroll
  for (int mi = 0; mi < MI; mi++) {
    int row = m0 + wm + mi * 16 + col_l;
    if (row >= M) row = M - 1;  // clamp; masked at store
    long grow = d.row_mode ? ((long)(row >> 2) * PP + (row & 3)) : (long)row;
    pA[mi] = d.A + grow * d.lda + quad * 8;
  }
  const __hip_bfloat16* pB[NI];
#pragma unroll
  for (int ni = 0; ni < NI; ni++) {
    int row = n0 + wn + ni * 16 + col_l;
    if (row >= N) row = N - 1;
    pB[ni] = d.BT + (long)row * d.ldbt + quad * 8;
  }

  f32x4v acc[MI][NI];
#pragma unroll
  for (int i = 0; i < MI; i++)
#pragma unroll
    for (int j = 0; j < NI; j++)
#pragma unroll
      for (int r = 0; r < 4; r++) acc[i][j][r] = 0.f;

  const int nk = d.K / TK;
  bf16x8v afc[MI], bfc[NI], afn[MI], bfn[NI];
#pragma unroll
  for (int mi = 0; mi < MI; mi++) afc[mi] = *(const bf16x8v*)(pA[mi]);
#pragma unroll
  for (int ni = 0; ni < NI; ni++) bfc[ni] = *(const bf16x8v*)(pB[ni]);

  for (int kt = 0; kt < nk; kt++) {
    const int knext = (kt + 1) * TK;
    if (kt + 1 < nk) {
#pragma unroll
      for (int mi = 0; mi < MI; mi++)
        afn[mi] = *(const bf16x8v*)(pA[mi] + knext);
#pragma unroll
      for (int ni = 0; ni < NI; ni++)
        bfn[ni] = *(const bf16x8v*)(pB[ni] + knext);
    }
#pragma unroll
    for (int mi = 0; mi < MI; mi++)
#pragma unroll
      for (int ni = 0; ni < NI; ni++)
        acc[mi][ni] = __builtin_amdgcn_mfma_f32_16x16x32_bf16(
            afc[mi], bfc[ni], acc[mi][ni], 0, 0, 0);
#pragma unroll
    for (int mi = 0; mi < MI; mi++) afc[mi] = afn[mi];
#pragma unroll
    for (int ni = 0; ni < NI; ni++) bfc[ni] = bfn[ni];
  }

  const int store_f32 =
      (d.c_mode == 1) || (d.c_mode == 2 && outflag && outflag[0]);
#pragma unroll
  for (int mi = 0; mi < MI; mi++) {
    int rbase = m0 + wm + mi * 16 + quad * 4;
#pragma unroll
    for (int ni = 0; ni < NI; ni++) {
      int col = n0 + wn + ni * 16 + col_l;
      if (col >= N) continue;
      float bv = d.bias ? __bfloat162float(d.bias[col]) : 0.f;
#pragma unroll
      for (int r = 0; r < 4; r++) {
        int row = rbase + r;
        if (row >= M) continue;
        float v = acc[mi][ni][r] + bv;
        if (d.do_relu) v = fmaxf(v, 0.f);
        if (store_f32)
          ((float*)d.C)[(long)row * d.ldc + col] = v;
        else
          ((__hip_bfloat16*)d.C)[(long)row * d.ldc + col] = __float2bfloat16(v);
      }
    }
  }
}

// ---------------------------------------------------------------------------
// Fused GAT (unchanged).
// ---------------------------------------------------------------------------
#define CHROW (DCAT / 4)

__global__ __launch_bounds__(1024) void attn_fused(
    const __hip_bfloat16* __restrict__ xcat,
    const __hip_bfloat16* __restrict__ hcat,
    const __hip_bfloat16* __restrict__ aV,
    const __hip_bfloat16* __restrict__ aL,
    __hip_bfloat16* __restrict__ newcat) {
  const int b = blockIdx.x;
  const int t = threadIdx.x;
  const long base = (long)b * PP * DCAT;

  __shared__ __hip_bfloat16 hs[PP][DCAT];
  __shared__ float esv[PP], edv[PP], esl[PP], edl[PP];
  __shared__ float alphaV[PP * PP], alphaL[PP * PP];

  for (int i = t; i < PP * CHROW; i += 1024) {
    int r = i / CHROW, c = (i % CHROW) * 4;
    *(u16x4*)&hs[r][c] = *(const u16x4*)(hcat + base + (long)r * DCAT + c);
  }
  __syncthreads();

  const int wave = t >> 6, lane = t & 63;
  for (int node = wave; node < PP; node += 16) {
    float s1 = 0.f, s2 = 0.f, s3 = 0.f, s4 = 0.f;
    for (int f = lane * 4; f < FF; f += 256) {
      u16x4 hv = *(const u16x4*)&hs[node][f];
      u16x4 a1 = *(const u16x4*)(aV + f);
      u16x4 a2 = *(const u16x4*)(aV + FF + f);
#pragma unroll
      for (int j = 0; j < 4; j++) {
        float hf = bf2f(hv[j]);
        s1 += hf * bf2f(a1[j]);
        s2 += hf * bf2f(a2[j]);
      }
    }
    for (int f = FF + lane * 4; f < FF + LL; f += 256) {
      u16x4 hv = *(const u16x4*)&hs[node][f];
      u16x4 a3 = *(const u16x4*)(aL + (f - FF));
      u16x4 a4 = *(const u16x4*)(aL + LL + (f - FF));
#pragma unroll
      for (int j = 0; j < 4; j++) {
        float hf = bf2f(hv[j]);
        s3 += hf * bf2f(a3[j]);
        s4 += hf * bf2f(a4[j]);
      }
    }
#pragma unroll
    for (int o = 32; o > 0; o >>= 1) {
      s1 += __shfl_down(s1, o);
      s2 += __shfl_down(s2, o);
      s3 += __shfl_down(s3, o);
      s4 += __shfl_down(s4, o);
    }
    if (lane == 0) {
      esv[node] = s1; edv[node] = s2; esl[node] = s3; edl[node] = s4;
    }
  }
  __syncthreads();

  if (t < 2 * PP) {
    const int strm = t / PP, dd = t % PP;
    const float* es = strm ? esl : esv;
    const float ed = strm ? edl[dd] : edv[dd];
    float lg[PP];
    float m = -1e30f;
#pragma unroll
    for (int s = 0; s < PP; s++) {
      float e;
      if (s == dd) e = -1e30f;
      else {
        float v = es[s] + ed;
        e = (v > 0.f) ? v : 0.2f * v;
      }
      lg[s] = e;
      m = fmaxf(m, e);
    }
    float sum = 0.f;
#pragma unroll
    for (int s = 0; s < PP; s++) {
      lg[s] = expf(lg[s] - m);
      sum += lg[s];
    }
    float inv = 1.f / (sum + 1e-9f);
    float* al = strm ? alphaL : alphaV;
#pragma unroll
    for (int s = 0; s < PP; s++) al[s * PP + dd] = lg[s] * inv;
  }
  __syncthreads();

  for (int i = t; i < PP * CHROW; i += 1024) {
    int dd = i / CHROW, c = (i % CHROW) * 4;
    u16x4 ov;
    if (c >= FF + LL) {
      ov[0] = 0; ov[1] = 0; ov[2] = 0; ov[3] = 0;
    } else {
      const float* al = (c < FF) ? (alphaV + dd) : (alphaL + dd);
      float a0 = 0.f, a1 = 0.f, a2 = 0.f, a3 = 0.f;
#pragma unroll
      for (int s = 0; s < PP; s++) {
        float w = al[s * PP];
        u16x4 hv = *(const u16x4*)&hs[s][c];
        a0 += w * bf2f(hv[0]);
        a1 += w * bf2f(hv[1]);
        a2 += w * bf2f(hv[2]);
        a3 += w * bf2f(hv[3]);
      }
      u16x4 xv = *(const u16x4*)(xcat + base + (long)dd * DCAT + c);
      ov[0] = f2b(fmaxf(bf2f(xv[0]) + a0, 0.f));
      ov[1] = f2b(fmaxf(bf2f(xv[1]) + a1, 0.f));
      ov[2] = f2b(fmaxf(bf2f(xv[2]) + a2, 0.f));
      ov[3] = f2b(fmaxf(bf2f(xv[3]) + a3, 0.f));
    }
    *(u16x4*)(newcat + base + (long)dd * DCAT + c) = ov;
  }
}

// ---------------------------------------------------------------------------
// Combine, 8 edges/block (unchanged).
// ---------------------------------------------------------------------------
__global__ __launch_bounds__(256) void combine_kernel(
    const int* __restrict__ e_src, const int* __restrict__ e_dst,
    const int* __restrict__ r_eid, const void* __restrict__ spat_raw,
    const __hip_bfloat16* __restrict__ W1sp,
    const __hip_bfloat16* __restrict__ b1,
    const __hip_bfloat16* __restrict__ Yd, const __hip_bfloat16* __restrict__ Ys,
    __hip_bfloat16* __restrict__ hdn, const int* __restrict__ flag) {
  const int t = threadIdx.x;
  const int e0 = blockIdx.x * EPB;
  const int hd = t * 4;

  float w[SS][4];
#pragma unroll
  for (int k = 0; k < SS; k++) {
    u16x4 ww = *(const u16x4*)(W1sp + (long)k * HDIM + hd);
#pragma unroll
    for (int j = 0; j < 4; j++) w[k][j] = bf2f(ww[j]);
  }
  float bb[4];
  {
    u16x4 bv = *(const u16x4*)(b1 + hd);
#pragma unroll
    for (int j = 0; j < 4; j++) bb[j] = bf2f(bv[j]);
  }

  __shared__ int sh_s[EPB], sh_hx[EPB], sh_re[EPB];
  __shared__ float sh_sf[EPB][SS];
  if (t < EPB) {
    int re = r_eid[e0 + t];
    sh_re[t] = re;
    sh_s[t] = e_src[re];
    int d = e_dst[re];
    sh_hx[t] = (d / PP) * HH + (d % PP);
  }
  __syncthreads();
  if (t < EPB * SS) {
    int ee = t >> 4, k = t & 15;
    long idx = (long)sh_re[ee] * SS + k;
    sh_sf[ee][k] = flag[0]
                       ? ((const float*)spat_raw)[idx]
                       : __bfloat162float(((const __hip_bfloat16*)spat_raw)[idx]);
  }
  __syncthreads();

#pragma unroll
  for (int ee = 0; ee < EPB; ee++) {
    const int s = sh_s[ee];
    const int hx = sh_hx[ee];
    u16x4 yd = *(const u16x4*)(Yd + (long)hx * HDIM + hd);
    u16x4 ys = *(const u16x4*)(Ys + (long)s * HDIM + hd);
    float v[4];
#pragma unroll
    for (int j = 0; j < 4; j++) v[j] = bf2f(yd[j]) + bf2f(ys[j]) + bb[j];
#pragma unroll
    for (int k = 0; k < SS; k++) {
      float sfv = sh_sf[ee][k];
#pragma unroll
      for (int j = 0; j < 4; j++) v[j] += sfv * w[k][j];
    }
    u16x4 o;
#pragma unroll
    for (int j = 0; j < 4; j++) o[j] = f2b(fmaxf(v[j], 0.f));
    *(u16x4*)(hdn + (long)(e0 + ee) * HDIM + hd) = o;
  }
}

// ---------------------------------------------------------------------------
extern "C" void kernel_launch(void* const* d_in, const int* in_sizes, int n_in,
                              void* d_out, int out_size, void* d_ws,
                              size_t ws_size, hipStream_t stream) {
  const int* e_src = (const int*)d_in[11];
  const int* e_dst = (const int*)d_in[12];
  const int* r_eid = (const int*)d_in[13];
  (void)ws_size; (void)n_in; (void)in_sizes; (void)out_size;

  char* ws = (char*)d_ws;
  size_t off = 0;
  auto take = [&](size_t bytes) {
    char* p = ws + off;
    off += (bytes + 255) & ~(size_t)255;
    return p;
  };

  int* dflag = (int*)take(256);
  __hip_bfloat16* xcat   = (__hip_bfloat16*)take((size_t)NNODE * DCAT * 2);
  __hip_bfloat16* hcat   = (__hip_bfloat16*)take((size_t)NNODE * DCAT * 2);
  __hip_bfloat16* newcat = (__hip_bfloat16*)take((size_t)NNODE * DCAT * 2);
  __hip_bfloat16* cAv    = (__hip_bfloat16*)take((size_t)2 * FF * 2);
  __hip_bfloat16* cAl    = (__hip_bfloat16*)take((size_t)2 * LL * 2);
  __hip_bfloat16* cB1    = (__hip_bfloat16*)take((size_t)HDIM * 2);
  __hip_bfloat16* cB2    = (__hip_bfloat16*)take((size_t)CC * 2);
  __hip_bfloat16* cW1sp  = (__hip_bfloat16*)take((size_t)SS * HDIM * 2);
  __hip_bfloat16* WvT    = (__hip_bfloat16*)take((size_t)FF * FF * 2);
  __hip_bfloat16* WlT    = (__hip_bfloat16*)take((size_t)LL * LLP * 2);
  __hip_bfloat16* W1Td   = (__hip_bfloat16*)take((size_t)HDIM * DCAT * 2);
  __hip_bfloat16* W1Ts   = (__hip_bfloat16*)take((size_t)HDIM * DCAT * 2);
  __hip_bfloat16* W2T    = (__hip_bfloat16*)take((size_t)CC * HDIM * 2);
  __hip_bfloat16* Yd     = (__hip_bfloat16*)take((size_t)BB * HH * HDIM * 2);
  __hip_bfloat16* Ys     = (__hip_bfloat16*)take((size_t)NNODE * HDIM * 2);
  __hip_bfloat16* hdn    = (__hip_bfloat16*)take((size_t)NREAD * HDIM * 2);

  dim3 blk(256);

  // 0) sniff dtype
  sniff_dtype<<<1, blk, 0, stream>>>((const unsigned short*)d_in[0], dflag);

  // 0b) ALL conversions + transposes in one launch
  prep_all<<<PREP_BLOCKS, blk, 0, stream>>>(
      d_in[0], d_in[1], d_in[3], d_in[4], d_in[5], d_in[6], d_in[7], d_in[8],
      d_in[9], d_in[10], xcat, cAv, cAl, cB1, cB2, cW1sp, WvT, WlT, W1Td, W1Ts,
      W2T, dflag);

  // 1) Projections (merged, direct-load GEMM)
  {
    GDesc pv{xcat, WvT, hcat, nullptr,
             NNODE, FF, FF, DCAT, FF, DCAT, 0, 0, 0, 8, 80};
    GDesc pl{xcat + FF, WlT, hcat + FF, nullptr,
             NNODE, LL, LLP, DCAT, LLP, DCAT, 0, 0, 0, 3, 80};
    gemm_direct<64, 128, 2, 2><<<dim3(8, 80, 2), blk, 0, stream>>>(pv, pl,
                                                                   nullptr);
  }

  // 2+3) Fused logits + segment-softmax + message + residual relu
  attn_fused<<<BB, dim3(1024), 0, stream>>>(xcat, hcat, cAv, cAl, newcat);

  // 4) Concat-K projections (merged, direct-load GEMM)
  {
    GDesc gys{newcat, W1Ts, Ys, nullptr,
              NNODE, HDIM, DCAT, DCAT, DCAT, HDIM, 0, 0, 0, 8, 80};
    GDesc gyd{newcat, W1Td, Yd, nullptr,
              BB * HH, HDIM, DCAT, DCAT, DCAT, HDIM, 1, 0, 0, 8, 16};
    gemm_direct<64, 128, 2, 2><<<dim3(8, 80, 2), blk, 0, stream>>>(gys, gyd,
                                                                   nullptr);
  }

  // 5) Combine + relu -> hdn
  combine_kernel<<<NREAD / EPB, blk, 0, stream>>>(e_src, e_dst, r_eid, d_in[2],
                                                  cW1sp, cB1, Yd, Ys, hdn,
                                                  dflag);

  // 6) out = hdn @ W2 + b2 (direct-load GEMM, 32x128)
  {
    GDesc go{hdn, W2T, d_out, cB2,
             NREAD, CC, HDIM, HDIM, HDIM, CC, 0, 0, 2, 1, 608};
    gemm_direct<32, 128, 1, 4><<<dim3(1, 608, 1), blk, 0, stream>>>(go, go,
                                                                    dflag);
  }
}

// Round 10
// 258.580 us; speedup vs baseline: 1.4480x; 1.4480x over previous
//
#include <hip/hip_runtime.h>
#include <hip/hip_bf16.h>

// Problem constants
#define BB 256
#define PP 20
#define HH 4
#define FF 1024
#define LL 300
#define LLP 320           // LL padded to 32-multiple
#define DCAT 1344         // FF + LLP
#define SS 16
#define HDIM 1024
#define CC 117
#define NNODE (BB * PP)              // 5120
#define NREAD (BB * (PP * HH - HH))  // 19456
#define TKB 64                       // staged GEMM K-tile (21 barriers @K=1344)

typedef __attribute__((ext_vector_type(8))) short bf16x8v;
typedef __attribute__((ext_vector_type(4))) float f32x4v;
typedef __attribute__((ext_vector_type(4))) unsigned short u16x4;

__device__ __forceinline__ float bf2f(unsigned short u) {
  return __uint_as_float((unsigned int)u << 16);
}
__device__ __forceinline__ unsigned short f2b(float f) {
  __hip_bfloat16 h = __float2bfloat16(f);
  return *(unsigned short*)&h;
}

// Block-local dtype sniff (ret 1 -> fp32 inputs). Reads 512 halfwords of
// feat; bf16 N(0,1) -> ~all magnitudes in [2^-30,2^30]; fp32-as-bf16 -> ~61%.
__device__ __forceinline__ int block_sniff(const unsigned short* fb, int t,
                                           int* sv) {
  int votes = 0;
  for (int i = t; i < 512; i += 256) {
    unsigned int u = (unsigned int)fb[i] << 16;
    float v = __uint_as_float(u);
    float a = fabsf(v);
    if (v == v && a > 9.3e-10f && a < 1.1e9f) votes++;
  }
  sv[t] = votes;
  __syncthreads();
  for (int s = 128; s > 0; s >>= 1) {
    if (t < s) sv[t] += sv[t + s];
    __syncthreads();
  }
  int fl = (sv[0] < 448) ? 1 : 0;
  __syncthreads();
  return fl;
}

// ---------------------------------------------------------------------------
// prep_all: ONE launch for every conversion/transpose; sniff inlined.
//   [0, 5120)        feat -> xcat cols [0,1024)
//   [5120, 6720)     w2v  -> xcat cols [1024,1344) pad
//   [6720, 6799)     small vectors (aV,aL,b1,b2,W1sp)
//   [6799, 10739)    7 weight transposes -> B^T buffers
// ---------------------------------------------------------------------------
#define NB_FEAT 5120
#define NB_W2V 1600
#define NB_SM 79
#define PREP_BLOCKS 10739

__global__ __launch_bounds__(256) void prep_all(
    const void* __restrict__ s0, const void* __restrict__ s1,
    const void* __restrict__ s3, const void* __restrict__ s4,
    const void* __restrict__ s5, const void* __restrict__ s6,
    const void* __restrict__ s7, const void* __restrict__ s8,
    const void* __restrict__ s9, const void* __restrict__ s10,
    __hip_bfloat16* __restrict__ xcat, __hip_bfloat16* __restrict__ cAv,
    __hip_bfloat16* __restrict__ cAl, __hip_bfloat16* __restrict__ cB1,
    __hip_bfloat16* __restrict__ cB2, __hip_bfloat16* __restrict__ cW1sp,
    __hip_bfloat16* __restrict__ dWvT, __hip_bfloat16* __restrict__ dWlT,
    __hip_bfloat16* __restrict__ dW1d, __hip_bfloat16* __restrict__ dW1s,
    __hip_bfloat16* __restrict__ dW2T) {
  const int bid = blockIdx.x;
  const int t = threadIdx.x;
  __shared__ int sv[256];
  const int fl = block_sniff((const unsigned short*)s0, t, sv);

  if (bid < NB_FEAT) {
    long i = (long)bid * 256 + t;
    int r = (int)(i >> 8);
    int c = ((int)i & 255) * 4;
    u16x4 o;
    if (fl) {
      float4 v = *(const float4*)((const float*)s0 + (long)r * FF + c);
      o[0] = f2b(v.x); o[1] = f2b(v.y); o[2] = f2b(v.z); o[3] = f2b(v.w);
    } else {
      o = *(const u16x4*)((const __hip_bfloat16*)s0 + (long)r * FF + c);
    }
    *(u16x4*)(xcat + (long)r * DCAT + c) = o;
  } else if (bid < NB_FEAT + NB_W2V) {
    long i = (long)(bid - NB_FEAT) * 256 + t;
    int r = (int)(i / 80), c = ((int)(i % 80)) * 4;
    u16x4 o;
    if (c + 4 <= LL) {
      if (fl) {
        const float* p = (const float*)s1 + (long)r * LL + c;
        o[0] = f2b(p[0]); o[1] = f2b(p[1]); o[2] = f2b(p[2]); o[3] = f2b(p[3]);
      } else {
        const __hip_bfloat16* p = (const __hip_bfloat16*)s1 + (long)r * LL + c;
        o[0] = *(const unsigned short*)(p + 0);
        o[1] = *(const unsigned short*)(p + 1);
        o[2] = *(const unsigned short*)(p + 2);
        o[3] = *(const unsigned short*)(p + 3);
      }
    } else {
#pragma unroll
      for (int j = 0; j < 4; j++) {
        float v = 0.f;
        if (c + j < LL)
          v = fl ? ((const float*)s1)[(long)r * LL + c + j]
                 : __bfloat162float(
                       ((const __hip_bfloat16*)s1)[(long)r * LL + c + j]);
        o[j] = f2b(v);
      }
    }
    *(u16x4*)(xcat + (long)r * DCAT + FF + c) = o;
  } else if (bid < NB_FEAT + NB_W2V + NB_SM) {
    int i = (bid - NB_FEAT - NB_W2V) * 256 + t;
    auto rd = [&](const void* p, long idx) -> float {
      return fl ? ((const float*)p)[idx]
                : __bfloat162float(((const __hip_bfloat16*)p)[idx]);
    };
    if (i < 2048) cAv[i] = __float2bfloat16(rd(s4, i));
    else if (i < 2648) cAl[i - 2048] = __float2bfloat16(rd(s6, i - 2048));
    else if (i < 3672) cB1[i - 2648] = __float2bfloat16(rd(s8, i - 2648));
    else if (i < 3789) cB2[i - 3672] = __float2bfloat16(rd(s10, i - 3672));
    else if (i < 20173)
      cW1sp[i - 3789] = __float2bfloat16(rd(s7, 1355776L + (i - 3789)));
  } else {
    int idx = bid - (NB_FEAT + NB_W2V + NB_SM);
    const int OFFS[8] = {0, 1024, 1124, 2148, 2468, 3492, 3812, 3940};
    const int NKB[7] = {32, 10, 32, 10, 32, 10, 32};
    const int ROW0[7] = {0, 0, 0, 1024, 1640, 1340, 0};
    const int KK[7] = {1024, 300, 1024, 300, 1024, 300, 1024};
    const int NN[7] = {1024, 300, 1024, 1024, 1024, 1024, 117};
    const int LD[7] = {1024, 300, 1024, 1024, 1024, 1024, 117};
    const int KP[7] = {1024, 320, 1024, 320, 1024, 320, 1024};
    const int KOFF[7] = {0, 0, 0, 1024, 0, 1024, 0};
    const int KLD[7] = {1024, 320, DCAT, DCAT, DCAT, DCAT, 1024};
    int z = 0;
    while (z < 6 && idx >= OFFS[z + 1]) z++;
    idx -= OFFS[z];
    const int kb = (idx % NKB[z]) * 32, nb = (idx / NKB[z]) * 32;
    const void* src = (z == 0) ? s3 : (z == 1) ? s5 : (z == 6) ? s9 : s7;
    __hip_bfloat16* dst = (z == 0) ? dWvT : (z == 1) ? dWlT
                          : (z <= 3) ? dW1d : (z <= 5) ? dW1s : dW2T;
    const int row0 = ROW0[z], K = KK[z], N = NN[z], ld = LD[z], Kp = KP[z];
    const int koff = KOFF[z], kld = KLD[z];
    __shared__ float tile[32][33];
    const int tx = t & 31, ty = t >> 5;
    for (int i = ty; i < 32; i += 8) {
      int k = kb + i, n = nb + tx;
      float v = 0.f;
      if (k < K && n < N) {
        long sidx = (long)(row0 + k) * ld + n;
        v = fl ? ((const float*)src)[sidx]
               : __bfloat162float(((const __hip_bfloat16*)src)[sidx]);
      }
      tile[i][tx] = v;
    }
    __syncthreads();
    for (int i = ty; i < 32; i += 8) {
      int n = nb + i, k = kb + tx;
      if (n < N && k < Kp)
        dst[(long)n * kld + koff + k] = __float2bfloat16(tile[tx][i]);
    }
  }
}

// ---------------------------------------------------------------------------
// Staged double-buffered MFMA GEMM (R8 structure) + TK=64 + XOR bank swizzle.
// C = A @ BT^T. Swizzle: global k-chunk kc lands in LDS row slot
// j = kc ^ (row&7); folded into the GLOBAL address at staging (LDS dst stays
// lane-linear per the global_load_lds constraint) and into the LDS read addr.
// Fragment reads go 8-way-conflicted -> 2-way (free).
// ---------------------------------------------------------------------------
struct GDesc {
  const __hip_bfloat16* A;
  const __hip_bfloat16* BT;
  void* C;
  const __hip_bfloat16* bias;
  int M, N, K, lda, ldbt, ldc;
  int row_mode, do_relu, c_fp32, nbx, nby;
};

template <int BM, int BN, int WR, int WC>
__global__ __launch_bounds__(256) void gemm_db(GDesc d0, GDesc d1) {
  constexpr int MI = BM / WR / 16;
  constexpr int NI = BN / WC / 16;
  __shared__ __hip_bfloat16 Asm[2][BM * TKB];
  __shared__ __hip_bfloat16 Bsm[2][BN * TKB];
  const GDesc d = blockIdx.z ? d1 : d0;
  if ((int)blockIdx.x >= d.nbx || (int)blockIdx.y >= d.nby) return;
  const int tid = threadIdx.x;
  const int lane = tid & 63;
  const int wave = tid >> 6;
  const int wm = (wave % WR) * (BM / WR);
  const int wn = (wave / WR) * (BN / WC);
  const int m0 = blockIdx.y * BM;
  const int n0 = blockIdx.x * BN;
  const int col_l = lane & 15;
  const int quad = lane >> 4;
  const __hip_bfloat16* A = d.A;
  const __hip_bfloat16* BT = d.BT;
  const int M = d.M, N = d.N, lda = d.lda, ldbt = d.ldbt;
  const int row_mode = d.row_mode;

  auto stage = [&](int k0, int buf) {
#pragma unroll
    for (int c = tid; c < BM * 8; c += 256) {
      int r = c >> 3, j = c & 7;
      int kc = j ^ (r & 7);  // swizzle on the global side
      int row = m0 + r;
      if (row >= M) row = M - 1;
      long grow = row_mode ? ((long)(row >> 2) * PP + (row & 3)) : (long)row;
      const __hip_bfloat16* gp = A + grow * lda + k0 + kc * 8;
      __builtin_amdgcn_global_load_lds(
          (const __attribute__((address_space(1))) unsigned int*)gp,
          (__attribute__((address_space(3))) unsigned int*)(&Asm[buf][c * 8]),
          16, 0, 0);
    }
#pragma unroll
    for (int c = tid; c < BN * 8; c += 256) {
      int r = c >> 3, j = c & 7;
      int kc = j ^ (r & 7);
      int row = n0 + r;
      if (row >= N) row = N - 1;
      const __hip_bfloat16* gp = BT + (long)row * ldbt + k0 + kc * 8;
      __builtin_amdgcn_global_load_lds(
          (const __attribute__((address_space(1))) unsigned int*)gp,
          (__attribute__((address_space(3))) unsigned int*)(&Bsm[buf][c * 8]),
          16, 0, 0);
    }
  };

  f32x4v acc[MI][NI];
#pragma unroll
  for (int i = 0; i < MI; i++)
#pragma unroll
    for (int j = 0; j < NI; j++)
#pragma unroll
      for (int r = 0; r < 4; r++) acc[i][j][r] = 0.f;

  const int nk = d.K / TKB;
  stage(0, 0);
  __syncthreads();
  for (int kt = 0; kt < nk; kt++) {
    const int cur = kt & 1;
    if (kt + 1 < nk) stage((kt + 1) * TKB, 1 - cur);
#pragma unroll
    for (int ks = 0; ks < 2; ks++) {
      bf16x8v af[MI], bfr[NI];
#pragma unroll
      for (int mi = 0; mi < MI; mi++) {
        int R = wm + mi * 16 + col_l;
        int j = (ks * 4 + quad) ^ (R & 7);
        af[mi] = *(const bf16x8v*)&Asm[cur][R * TKB + j * 8];
      }
#pragma unroll
      for (int ni = 0; ni < NI; ni++) {
        int R = wn + ni * 16 + col_l;
        int j = (ks * 4 + quad) ^ (R & 7);
        bfr[ni] = *(const bf16x8v*)&Bsm[cur][R * TKB + j * 8];
      }
#pragma unroll
      for (int mi = 0; mi < MI; mi++)
#pragma unroll
        for (int ni = 0; ni < NI; ni++)
          acc[mi][ni] = __builtin_amdgcn_mfma_f32_16x16x32_bf16(
              af[mi], bfr[ni], acc[mi][ni], 0, 0, 0);
    }
    __syncthreads();
  }

#pragma unroll
  for (int mi = 0; mi < MI; mi++) {
    int rbase = m0 + wm + mi * 16 + quad * 4;
#pragma unroll
    for (int ni = 0; ni < NI; ni++) {
      int col = n0 + wn + ni * 16 + col_l;
      if (col >= N) continue;
      float bv = d.bias ? __bfloat162float(d.bias[col]) : 0.f;
#pragma unroll
      for (int r = 0; r < 4; r++) {
        int row = rbase + r;
        if (row >= M) continue;
        float v = acc[mi][ni][r] + bv;
        if (d.do_relu) v = fmaxf(v, 0.f);
        if (d.c_fp32)
          ((float*)d.C)[(long)row * d.ldc + col] = v;
        else
          ((__hip_bfloat16*)d.C)[(long)row * d.ldc + col] = __float2bfloat16(v);
      }
    }
  }
}

// ---------------------------------------------------------------------------
// Fused GAT (unchanged).
// ---------------------------------------------------------------------------
#define CHROW (DCAT / 4)

__global__ __launch_bounds__(1024) void attn_fused(
    const __hip_bfloat16* __restrict__ xcat,
    const __hip_bfloat16* __restrict__ hcat,
    const __hip_bfloat16* __restrict__ aV,
    const __hip_bfloat16* __restrict__ aL,
    __hip_bfloat16* __restrict__ newcat) {
  const int b = blockIdx.x;
  const int t = threadIdx.x;
  const long base = (long)b * PP * DCAT;

  __shared__ __hip_bfloat16 hs[PP][DCAT];
  __shared__ float esv[PP], edv[PP], esl[PP], edl[PP];
  __shared__ float alphaV[PP * PP], alphaL[PP * PP];

  for (int i = t; i < PP * CHROW; i += 1024) {
    int r = i / CHROW, c = (i % CHROW) * 4;
    *(u16x4*)&hs[r][c] = *(const u16x4*)(hcat + base + (long)r * DCAT + c);
  }
  __syncthreads();

  const int wave = t >> 6, lane = t & 63;
  for (int node = wave; node < PP; node += 16) {
    float s1 = 0.f, s2 = 0.f, s3 = 0.f, s4 = 0.f;
    for (int f = lane * 4; f < FF; f += 256) {
      u16x4 hv = *(const u16x4*)&hs[node][f];
      u16x4 a1 = *(const u16x4*)(aV + f);
      u16x4 a2 = *(const u16x4*)(aV + FF + f);
#pragma unroll
      for (int j = 0; j < 4; j++) {
        float hf = bf2f(hv[j]);
        s1 += hf * bf2f(a1[j]);
        s2 += hf * bf2f(a2[j]);
      }
    }
    for (int f = FF + lane * 4; f < FF + LL; f += 256) {
      u16x4 hv = *(const u16x4*)&hs[node][f];
      u16x4 a3 = *(const u16x4*)(aL + (f - FF));
      u16x4 a4 = *(const u16x4*)(aL + LL + (f - FF));
#pragma unroll
      for (int j = 0; j < 4; j++) {
        float hf = bf2f(hv[j]);
        s3 += hf * bf2f(a3[j]);
        s4 += hf * bf2f(a4[j]);
      }
    }
#pragma unroll
    for (int o = 32; o > 0; o >>= 1) {
      s1 += __shfl_down(s1, o);
      s2 += __shfl_down(s2, o);
      s3 += __shfl_down(s3, o);
      s4 += __shfl_down(s4, o);
    }
    if (lane == 0) {
      esv[node] = s1; edv[node] = s2; esl[node] = s3; edl[node] = s4;
    }
  }
  __syncthreads();

  if (t < 2 * PP) {
    const int strm = t / PP, dd = t % PP;
    const float* es = strm ? esl : esv;
    const float ed = strm ? edl[dd] : edv[dd];
    float lg[PP];
    float m = -1e30f;
#pragma unroll
    for (int s = 0; s < PP; s++) {
      float e;
      if (s == dd) e = -1e30f;
      else {
        float v = es[s] + ed;
        e = (v > 0.f) ? v : 0.2f * v;
      }
      lg[s] = e;
      m = fmaxf(m, e);
    }
    float sum = 0.f;
#pragma unroll
    for (int s = 0; s < PP; s++) {
      lg[s] = expf(lg[s] - m);
      sum += lg[s];
    }
    float inv = 1.f / (sum + 1e-9f);
    float* al = strm ? alphaL : alphaV;
#pragma unroll
    for (int s = 0; s < PP; s++) al[s * PP + dd] = lg[s] * inv;
  }
  __syncthreads();

  for (int i = t; i < PP * CHROW; i += 1024) {
    int dd = i / CHROW, c = (i % CHROW) * 4;
    u16x4 ov;
    if (c >= FF + LL) {
      ov[0] = 0; ov[1] = 0; ov[2] = 0; ov[3] = 0;
    } else {
      const float* al = (c < FF) ? (alphaV + dd) : (alphaL + dd);
      float a0 = 0.f, a1 = 0.f, a2 = 0.f, a3 = 0.f;
#pragma unroll
      for (int s = 0; s < PP; s++) {
        float w = al[s * PP];
        u16x4 hv = *(const u16x4*)&hs[s][c];
        a0 += w * bf2f(hv[0]);
        a1 += w * bf2f(hv[1]);
        a2 += w * bf2f(hv[2]);
        a3 += w * bf2f(hv[3]);
      }
      u16x4 xv = *(const u16x4*)(xcat + base + (long)dd * DCAT + c);
      ov[0] = f2b(fmaxf(bf2f(xv[0]) + a0, 0.f));
      ov[1] = f2b(fmaxf(bf2f(xv[1]) + a1, 0.f));
      ov[2] = f2b(fmaxf(bf2f(xv[2]) + a2, 0.f));
      ov[3] = f2b(fmaxf(bf2f(xv[3]) + a3, 0.f));
    }
    *(u16x4*)(newcat + base + (long)dd * DCAT + c) = ov;
  }
}

// ---------------------------------------------------------------------------
// FUSED combine + output GEMM. 32 edges/block (608 blocks).
// Phase A: hdn rows for 32 edges built into LDS (66 KB, row stride 1032
//   elems -> 4-bank rotation, 2-way max).
// Phase B: out[32 x 117] = hs @ W2T^T via MFMA; A from LDS (no barriers in
//   K-loop — hs is read-only), B = W2T (0.23 MB, per-XCD-L2-resident) loaded
//   direct per-lane with 1-deep register pipeline. Saves the 80 MB hdn
//   HBM round-trip + one launch. Output dtype via inline sniff.
// ---------------------------------------------------------------------------
#define HSLD 1032  // hs row stride (elements)

__global__ __launch_bounds__(256) void combine_out(
    const int* __restrict__ e_src, const int* __restrict__ e_dst,
    const int* __restrict__ r_eid, const void* __restrict__ spat_raw,
    const void* __restrict__ feat_raw, const __hip_bfloat16* __restrict__ W1sp,
    const __hip_bfloat16* __restrict__ b1,
    const __hip_bfloat16* __restrict__ Yd, const __hip_bfloat16* __restrict__ Ys,
    const __hip_bfloat16* __restrict__ W2T,
    const __hip_bfloat16* __restrict__ b2, void* __restrict__ out) {
  const int t = threadIdx.x;
  const int e0 = blockIdx.x * 32;
  __shared__ unsigned short hs[32][HSLD];   // 66 KB
  __shared__ int sv[256];
  __shared__ int sh_s[32], sh_hx[32], sh_re[32];
  __shared__ float sh_sf[32][SS];

  const int fl = block_sniff((const unsigned short*)feat_raw, t, sv);

  // ---- Phase A: combine into LDS
  const int hd = t * 4;
  float w[SS][4];
#pragma unroll
  for (int k = 0; k < SS; k++) {
    u16x4 ww = *(const u16x4*)(W1sp + (long)k * HDIM + hd);
#pragma unroll
    for (int j = 0; j < 4; j++) w[k][j] = bf2f(ww[j]);
  }
  float bb[4];
  {
    u16x4 bv = *(const u16x4*)(b1 + hd);
#pragma unroll
    for (int j = 0; j < 4; j++) bb[j] = bf2f(bv[j]);
  }

  if (t < 32) {
    int re = r_eid[e0 + t];
    sh_re[t] = re;
    sh_s[t] = e_src[re];
    int d = e_dst[re];
    sh_hx[t] = (d / PP) * HH + (d % PP);
  }
  __syncthreads();
  {
    // 32 edges x 16 spatial = 512 values; 2 per thread
#pragma unroll
    for (int p = 0; p < 2; p++) {
      int i = t + p * 256;
      int ee = i >> 4, k = i & 15;
      long idx = (long)sh_re[ee] * SS + k;
      sh_sf[ee][k] =
          fl ? ((const float*)spat_raw)[idx]
             : __bfloat162float(((const __hip_bfloat16*)spat_raw)[idx]);
    }
  }
  __syncthreads();

#pragma unroll 4
  for (int ee = 0; ee < 32; ee++) {
    const int s = sh_s[ee];
    const int hx = sh_hx[ee];
    u16x4 yd = *(const u16x4*)(Yd + (long)hx * HDIM + hd);
    u16x4 ys = *(const u16x4*)(Ys + (long)s * HDIM + hd);
    float v[4];
#pragma unroll
    for (int j = 0; j < 4; j++) v[j] = bf2f(yd[j]) + bf2f(ys[j]) + bb[j];
#pragma unroll
    for (int k = 0; k < SS; k++) {
      float sfv = sh_sf[ee][k];
#pragma unroll
      for (int j = 0; j < 4; j++) v[j] += sfv * w[k][j];
    }
    u16x4 o;
#pragma unroll
    for (int j = 0; j < 4; j++) o[j] = f2b(fmaxf(v[j], 0.f));
    *(u16x4*)&hs[ee][hd] = o;
  }
  __syncthreads();

  // ---- Phase B: out tile = hs[32 x 1024] @ W2T[117 x 1024]^T
  const int lane = t & 63;
  const int wave = t >> 6;
  const int col_l = lane & 15;
  const int quad = lane >> 4;
  const int wn = wave * 32;  // waves split N=128(117) into 4 x 32

  const __hip_bfloat16* pB[2];
#pragma unroll
  for (int ni = 0; ni < 2; ni++) {
    int n = wn + ni * 16 + col_l;
    if (n >= CC) n = CC - 1;
    pB[ni] = W2T + (long)n * HDIM + quad * 8;
  }

  f32x4v acc[2][2];
#pragma unroll
  for (int i = 0; i < 2; i++)
#pragma unroll
    for (int j = 0; j < 2; j++)
#pragma unroll
      for (int r = 0; r < 4; r++) acc[i][j][r] = 0.f;

  bf16x8v bcur[2], bnext[2];
#pragma unroll
  for (int ni = 0; ni < 2; ni++) bcur[ni] = *(const bf16x8v*)(pB[ni]);

  for (int kt = 0; kt < HDIM / 32; kt++) {
    const int k0 = kt * 32;
    if (kt + 1 < HDIM / 32) {
#pragma unroll
      for (int ni = 0; ni < 2; ni++)
        bnext[ni] = *(const bf16x8v*)(pB[ni] + (kt + 1) * 32);
    }
    bf16x8v af[2];
#pragma unroll
    for (int mi = 0; mi < 2; mi++)
      af[mi] = *(const bf16x8v*)&hs[mi * 16 + col_l][k0 + quad * 8];
#pragma unroll
    for (int mi = 0; mi < 2; mi++)
#pragma unroll
      for (int ni = 0; ni < 2; ni++)
        acc[mi][ni] = __builtin_amdgcn_mfma_f32_16x16x32_bf16(
            af[mi], bcur[ni], acc[mi][ni], 0, 0, 0);
#pragma unroll
    for (int ni = 0; ni < 2; ni++) bcur[ni] = bnext[ni];
  }

#pragma unroll
  for (int mi = 0; mi < 2; mi++) {
    int rbase = mi * 16 + quad * 4;
#pragma unroll
    for (int ni = 0; ni < 2; ni++) {
      int col = wn + ni * 16 + col_l;
      if (col >= CC) continue;
      float bv = __bfloat162float(b2[col]);
#pragma unroll
      for (int r = 0; r < 4; r++) {
        long row = e0 + rbase + r;
        float v = acc[mi][ni][r] + bv;
        if (fl)
          ((float*)out)[row * CC + col] = v;
        else
          ((__hip_bfloat16*)out)[row * CC + col] = __float2bfloat16(v);
      }
    }
  }
}

// ---------------------------------------------------------------------------
extern "C" void kernel_launch(void* const* d_in, const int* in_sizes, int n_in,
                              void* d_out, int out_size, void* d_ws,
                              size_t ws_size, hipStream_t stream) {
  const int* e_src = (const int*)d_in[11];
  const int* e_dst = (const int*)d_in[12];
  const int* r_eid = (const int*)d_in[13];
  (void)ws_size; (void)n_in; (void)in_sizes; (void)out_size;

  char* ws = (char*)d_ws;
  size_t off = 0;
  auto take = [&](size_t bytes) {
    char* p = ws + off;
    off += (bytes + 255) & ~(size_t)255;
    return p;
  };

  __hip_bfloat16* xcat   = (__hip_bfloat16*)take((size_t)NNODE * DCAT * 2);
  __hip_bfloat16* hcat   = (__hip_bfloat16*)take((size_t)NNODE * DCAT * 2);
  __hip_bfloat16* newcat = (__hip_bfloat16*)take((size_t)NNODE * DCAT * 2);
  __hip_bfloat16* cAv    = (__hip_bfloat16*)take((size_t)2 * FF * 2);
  __hip_bfloat16* cAl    = (__hip_bfloat16*)take((size_t)2 * LL * 2);
  __hip_bfloat16* cB1    = (__hip_bfloat16*)take((size_t)HDIM * 2);
  __hip_bfloat16* cB2    = (__hip_bfloat16*)take((size_t)CC * 2);
  __hip_bfloat16* cW1sp  = (__hip_bfloat16*)take((size_t)SS * HDIM * 2);
  __hip_bfloat16* WvT    = (__hip_bfloat16*)take((size_t)FF * FF * 2);
  __hip_bfloat16* WlT    = (__hip_bfloat16*)take((size_t)LL * LLP * 2);
  __hip_bfloat16* W1Td   = (__hip_bfloat16*)take((size_t)HDIM * DCAT * 2);
  __hip_bfloat16* W1Ts   = (__hip_bfloat16*)take((size_t)HDIM * DCAT * 2);
  __hip_bfloat16* W2T    = (__hip_bfloat16*)take((size_t)CC * HDIM * 2);
  __hip_bfloat16* Yd     = (__hip_bfloat16*)take((size_t)BB * HH * HDIM * 2);
  __hip_bfloat16* Ys     = (__hip_bfloat16*)take((size_t)NNODE * HDIM * 2);

  dim3 blk(256);

  // 1) ALL conversions + transposes (sniff inlined)
  prep_all<<<PREP_BLOCKS, blk, 0, stream>>>(
      d_in[0], d_in[1], d_in[3], d_in[4], d_in[5], d_in[6], d_in[7], d_in[8],
      d_in[9], d_in[10], xcat, cAv, cAl, cB1, cB2, cW1sp, WvT, WlT, W1Td, W1Ts,
      W2T);

  // 2) Projections (merged, staged dbuf GEMM, TK=64 + swizzle)
  {
    GDesc pv{xcat, WvT, hcat, nullptr,
             NNODE, FF, FF, DCAT, FF, DCAT, 0, 0, 0, 8, 80};
    GDesc pl{xcat + FF, WlT, hcat + FF, nullptr,
             NNODE, LL, LLP, DCAT, LLP, DCAT, 0, 0, 0, 3, 80};
    gemm_db<64, 128, 2, 2><<<dim3(8, 80, 2), blk, 0, stream>>>(pv, pl);
  }

  // 3) Fused logits + segment-softmax + message + residual relu
  attn_fused<<<BB, dim3(1024), 0, stream>>>(xcat, hcat, cAv, cAl, newcat);

  // 4) Concat-K projections (merged)
  {
    GDesc gys{newcat, W1Ts, Ys, nullptr,
              NNODE, HDIM, DCAT, DCAT, DCAT, HDIM, 0, 0, 0, 8, 80};
    GDesc gyd{newcat, W1Td, Yd, nullptr,
              BB * HH, HDIM, DCAT, DCAT, DCAT, HDIM, 1, 0, 0, 8, 16};
    gemm_db<64, 128, 2, 2><<<dim3(8, 80, 2), blk, 0, stream>>>(gys, gyd);
  }

  // 5) FUSED combine + output GEMM (sniff inlined; out dtype per flag)
  combine_out<<<NREAD / 32, blk, 0, stream>>>(e_src, e_dst, r_eid, d_in[2],
                                              d_in[0], cW1sp, cB1, Yd, Ys, W2T,
                                              cB2, d_out);
}

// Round 11
// 233.282 us; speedup vs baseline: 1.6050x; 1.1084x over previous
//
#include <hip/hip_runtime.h>
#include <hip/hip_bf16.h>

// Problem constants
#define BB 256
#define PP 20
#define HH 4
#define FF 1024
#define LL 300
#define LLP 320           // LL padded to 32-multiple
#define DCAT 1344         // FF + LLP
#define SS 16
#define HDIM 1024
#define CC 117
#define NNODE (BB * PP)              // 5120
#define NREAD (BB * (PP * HH - HH))  // 19456
#define EPB 8                        // edges per combine block
#define TKB 64                       // staged GEMM K-tile

typedef __attribute__((ext_vector_type(8))) short bf16x8v;
typedef __attribute__((ext_vector_type(4))) float f32x4v;
typedef __attribute__((ext_vector_type(4))) unsigned short u16x4;

__device__ __forceinline__ float bf2f(unsigned short u) {
  return __uint_as_float((unsigned int)u << 16);
}
__device__ __forceinline__ unsigned short f2b(float f) {
  __hip_bfloat16 h = __float2bfloat16(f);
  return *(unsigned short*)&h;
}

// Block-local dtype sniff (ret 1 -> fp32 inputs).
__device__ __forceinline__ int block_sniff(const unsigned short* fb, int t,
                                           int* sv) {
  int votes = 0;
  for (int i = t; i < 512; i += 256) {
    unsigned int u = (unsigned int)fb[i] << 16;
    float v = __uint_as_float(u);
    float a = fabsf(v);
    if (v == v && a > 9.3e-10f && a < 1.1e9f) votes++;
  }
  sv[t] = votes;
  __syncthreads();
  for (int s = 128; s > 0; s >>= 1) {
    if (t < s) sv[t] += sv[t + s];
    __syncthreads();
  }
  int fl = (sv[0] < 448) ? 1 : 0;
  __syncthreads();
  return fl;
}

// ---------------------------------------------------------------------------
// prep_all: ONE launch for every conversion/transpose; sniff inlined.
// Block 0 persists the flag to dflag for downstream kernels.
// ---------------------------------------------------------------------------
#define NB_FEAT 5120
#define NB_W2V 1600
#define NB_SM 79
#define PREP_BLOCKS 10739

__global__ __launch_bounds__(256) void prep_all(
    const void* __restrict__ s0, const void* __restrict__ s1,
    const void* __restrict__ s3, const void* __restrict__ s4,
    const void* __restrict__ s5, const void* __restrict__ s6,
    const void* __restrict__ s7, const void* __restrict__ s8,
    const void* __restrict__ s9, const void* __restrict__ s10,
    __hip_bfloat16* __restrict__ xcat, __hip_bfloat16* __restrict__ cAv,
    __hip_bfloat16* __restrict__ cAl, __hip_bfloat16* __restrict__ cB1,
    __hip_bfloat16* __restrict__ cB2, __hip_bfloat16* __restrict__ cW1sp,
    __hip_bfloat16* __restrict__ dWvT, __hip_bfloat16* __restrict__ dWlT,
    __hip_bfloat16* __restrict__ dW1d, __hip_bfloat16* __restrict__ dW1s,
    __hip_bfloat16* __restrict__ dW2T, int* __restrict__ dflag) {
  const int bid = blockIdx.x;
  const int t = threadIdx.x;
  __shared__ int sv[256];
  const int fl = block_sniff((const unsigned short*)s0, t, sv);
  if (bid == 0 && t == 0) dflag[0] = fl;

  if (bid < NB_FEAT) {
    long i = (long)bid * 256 + t;
    int r = (int)(i >> 8);
    int c = ((int)i & 255) * 4;
    u16x4 o;
    if (fl) {
      float4 v = *(const float4*)((const float*)s0 + (long)r * FF + c);
      o[0] = f2b(v.x); o[1] = f2b(v.y); o[2] = f2b(v.z); o[3] = f2b(v.w);
    } else {
      o = *(const u16x4*)((const __hip_bfloat16*)s0 + (long)r * FF + c);
    }
    *(u16x4*)(xcat + (long)r * DCAT + c) = o;
  } else if (bid < NB_FEAT + NB_W2V) {
    long i = (long)(bid - NB_FEAT) * 256 + t;
    int r = (int)(i / 80), c = ((int)(i % 80)) * 4;
    u16x4 o;
    if (c + 4 <= LL) {
      if (fl) {
        const float* p = (const float*)s1 + (long)r * LL + c;
        o[0] = f2b(p[0]); o[1] = f2b(p[1]); o[2] = f2b(p[2]); o[3] = f2b(p[3]);
      } else {
        const __hip_bfloat16* p = (const __hip_bfloat16*)s1 + (long)r * LL + c;
        o[0] = *(const unsigned short*)(p + 0);
        o[1] = *(const unsigned short*)(p + 1);
        o[2] = *(const unsigned short*)(p + 2);
        o[3] = *(const unsigned short*)(p + 3);
      }
    } else {
#pragma unroll
      for (int j = 0; j < 4; j++) {
        float v = 0.f;
        if (c + j < LL)
          v = fl ? ((const float*)s1)[(long)r * LL + c + j]
                 : __bfloat162float(
                       ((const __hip_bfloat16*)s1)[(long)r * LL + c + j]);
        o[j] = f2b(v);
      }
    }
    *(u16x4*)(xcat + (long)r * DCAT + FF + c) = o;
  } else if (bid < NB_FEAT + NB_W2V + NB_SM) {
    int i = (bid - NB_FEAT - NB_W2V) * 256 + t;
    auto rd = [&](const void* p, long idx) -> float {
      return fl ? ((const float*)p)[idx]
                : __bfloat162float(((const __hip_bfloat16*)p)[idx]);
    };
    if (i < 2048) cAv[i] = __float2bfloat16(rd(s4, i));
    else if (i < 2648) cAl[i - 2048] = __float2bfloat16(rd(s6, i - 2048));
    else if (i < 3672) cB1[i - 2648] = __float2bfloat16(rd(s8, i - 2648));
    else if (i < 3789) cB2[i - 3672] = __float2bfloat16(rd(s10, i - 3672));
    else if (i < 20173)
      cW1sp[i - 3789] = __float2bfloat16(rd(s7, 1355776L + (i - 3789)));
  } else {
    int idx = bid - (NB_FEAT + NB_W2V + NB_SM);
    const int OFFS[8] = {0, 1024, 1124, 2148, 2468, 3492, 3812, 3940};
    const int NKB[7] = {32, 10, 32, 10, 32, 10, 32};
    const int ROW0[7] = {0, 0, 0, 1024, 1640, 1340, 0};
    const int KK[7] = {1024, 300, 1024, 300, 1024, 300, 1024};
    const int NN[7] = {1024, 300, 1024, 1024, 1024, 1024, 117};
    const int LD[7] = {1024, 300, 1024, 1024, 1024, 1024, 117};
    const int KP[7] = {1024, 320, 1024, 320, 1024, 320, 1024};
    const int KOFF[7] = {0, 0, 0, 1024, 0, 1024, 0};
    const int KLD[7] = {1024, 320, DCAT, DCAT, DCAT, DCAT, 1024};
    int z = 0;
    while (z < 6 && idx >= OFFS[z + 1]) z++;
    idx -= OFFS[z];
    const int kb = (idx % NKB[z]) * 32, nb = (idx / NKB[z]) * 32;
    const void* src = (z == 0) ? s3 : (z == 1) ? s5 : (z == 6) ? s9 : s7;
    __hip_bfloat16* dst = (z == 0) ? dWvT : (z == 1) ? dWlT
                          : (z <= 3) ? dW1d : (z <= 5) ? dW1s : dW2T;
    const int row0 = ROW0[z], K = KK[z], N = NN[z], ld = LD[z], Kp = KP[z];
    const int koff = KOFF[z], kld = KLD[z];
    __shared__ float tile[32][33];
    const int tx = t & 31, ty = t >> 5;
    for (int i = ty; i < 32; i += 8) {
      int k = kb + i, n = nb + tx;
      float v = 0.f;
      if (k < K && n < N) {
        long sidx = (long)(row0 + k) * ld + n;
        v = fl ? ((const float*)src)[sidx]
               : __bfloat162float(((const __hip_bfloat16*)src)[sidx]);
      }
      tile[i][tx] = v;
    }
    __syncthreads();
    for (int i = ty; i < 32; i += 8) {
      int n = nb + i, k = kb + tx;
      if (n < N && k < Kp)
        dst[(long)n * kld + koff + k] = __float2bfloat16(tile[tx][i]);
    }
  }
}

// ---------------------------------------------------------------------------
// Staged double-buffered MFMA GEMM, TK=64 + XOR bank swizzle (R10 GEMM).
// c_mode: 0 bf16, 1 fp32, 2 branch on outflag[0] (1 -> fp32).
// ---------------------------------------------------------------------------
struct GDesc {
  const __hip_bfloat16* A;
  const __hip_bfloat16* BT;
  void* C;
  const __hip_bfloat16* bias;
  int M, N, K, lda, ldbt, ldc;
  int row_mode, do_relu, c_mode, nbx, nby;
};

template <int BM, int BN, int WR, int WC>
__global__ __launch_bounds__(256) void gemm_db(GDesc d0, GDesc d1,
                                               const int* outflag) {
  constexpr int MI = BM / WR / 16;
  constexpr int NI = BN / WC / 16;
  __shared__ __hip_bfloat16 Asm[2][BM * TKB];
  __shared__ __hip_bfloat16 Bsm[2][BN * TKB];
  const GDesc d = blockIdx.z ? d1 : d0;
  if ((int)blockIdx.x >= d.nbx || (int)blockIdx.y >= d.nby) return;
  const int tid = threadIdx.x;
  const int lane = tid & 63;
  const int wave = tid >> 6;
  const int wm = (wave % WR) * (BM / WR);
  const int wn = (wave / WR) * (BN / WC);
  const int m0 = blockIdx.y * BM;
  const int n0 = blockIdx.x * BN;
  const int col_l = lane & 15;
  const int quad = lane >> 4;
  const __hip_bfloat16* A = d.A;
  const __hip_bfloat16* BT = d.BT;
  const int M = d.M, N = d.N, lda = d.lda, ldbt = d.ldbt;
  const int row_mode = d.row_mode;

  auto stage = [&](int k0, int buf) {
#pragma unroll
    for (int c = tid; c < BM * 8; c += 256) {
      int r = c >> 3, j = c & 7;
      int kc = j ^ (r & 7);  // swizzle folded into global source address
      int row = m0 + r;
      if (row >= M) row = M - 1;
      long grow = row_mode ? ((long)(row >> 2) * PP + (row & 3)) : (long)row;
      const __hip_bfloat16* gp = A + grow * lda + k0 + kc * 8;
      __builtin_amdgcn_global_load_lds(
          (const __attribute__((address_space(1))) unsigned int*)gp,
          (__attribute__((address_space(3))) unsigned int*)(&Asm[buf][c * 8]),
          16, 0, 0);
    }
#pragma unroll
    for (int c = tid; c < BN * 8; c += 256) {
      int r = c >> 3, j = c & 7;
      int kc = j ^ (r & 7);
      int row = n0 + r;
      if (row >= N) row = N - 1;
      const __hip_bfloat16* gp = BT + (long)row * ldbt + k0 + kc * 8;
      __builtin_amdgcn_global_load_lds(
          (const __attribute__((address_space(1))) unsigned int*)gp,
          (__attribute__((address_space(3))) unsigned int*)(&Bsm[buf][c * 8]),
          16, 0, 0);
    }
  };

  f32x4v acc[MI][NI];
#pragma unroll
  for (int i = 0; i < MI; i++)
#pragma unroll
    for (int j = 0; j < NI; j++)
#pragma unroll
      for (int r = 0; r < 4; r++) acc[i][j][r] = 0.f;

  const int nk = d.K / TKB;
  stage(0, 0);
  __syncthreads();
  for (int kt = 0; kt < nk; kt++) {
    const int cur = kt & 1;
    if (kt + 1 < nk) stage((kt + 1) * TKB, 1 - cur);
#pragma unroll
    for (int ks = 0; ks < 2; ks++) {
      bf16x8v af[MI], bfr[NI];
#pragma unroll
      for (int mi = 0; mi < MI; mi++) {
        int R = wm + mi * 16 + col_l;
        int j = (ks * 4 + quad) ^ (R & 7);
        af[mi] = *(const bf16x8v*)&Asm[cur][R * TKB + j * 8];
      }
#pragma unroll
      for (int ni = 0; ni < NI; ni++) {
        int R = wn + ni * 16 + col_l;
        int j = (ks * 4 + quad) ^ (R & 7);
        bfr[ni] = *(const bf16x8v*)&Bsm[cur][R * TKB + j * 8];
      }
#pragma unroll
      for (int mi = 0; mi < MI; mi++)
#pragma unroll
        for (int ni = 0; ni < NI; ni++)
          acc[mi][ni] = __builtin_amdgcn_mfma_f32_16x16x32_bf16(
              af[mi], bfr[ni], acc[mi][ni], 0, 0, 0);
    }
    __syncthreads();
  }

  const int store_f32 =
      (d.c_mode == 1) || (d.c_mode == 2 && outflag && outflag[0]);
#pragma unroll
  for (int mi = 0; mi < MI; mi++) {
    int rbase = m0 + wm + mi * 16 + quad * 4;
#pragma unroll
    for (int ni = 0; ni < NI; ni++) {
      int col = n0 + wn + ni * 16 + col_l;
      if (col >= N) continue;
      float bv = d.bias ? __bfloat162float(d.bias[col]) : 0.f;
#pragma unroll
      for (int r = 0; r < 4; r++) {
        int row = rbase + r;
        if (row >= M) continue;
        float v = acc[mi][ni][r] + bv;
        if (d.do_relu) v = fmaxf(v, 0.f);
        if (store_f32)
          ((float*)d.C)[(long)row * d.ldc + col] = v;
        else
          ((__hip_bfloat16*)d.C)[(long)row * d.ldc + col] = __float2bfloat16(v);
      }
    }
  }
}

// ---------------------------------------------------------------------------
// Fused GAT (unchanged).
// ---------------------------------------------------------------------------
#define CHROW (DCAT / 4)

__global__ __launch_bounds__(1024) void attn_fused(
    const __hip_bfloat16* __restrict__ xcat,
    const __hip_bfloat16* __restrict__ hcat,
    const __hip_bfloat16* __restrict__ aV,
    const __hip_bfloat16* __restrict__ aL,
    __hip_bfloat16* __restrict__ newcat) {
  const int b = blockIdx.x;
  const int t = threadIdx.x;
  const long base = (long)b * PP * DCAT;

  __shared__ __hip_bfloat16 hs[PP][DCAT];
  __shared__ float esv[PP], edv[PP], esl[PP], edl[PP];
  __shared__ float alphaV[PP * PP], alphaL[PP * PP];

  for (int i = t; i < PP * CHROW; i += 1024) {
    int r = i / CHROW, c = (i % CHROW) * 4;
    *(u16x4*)&hs[r][c] = *(const u16x4*)(hcat + base + (long)r * DCAT + c);
  }
  __syncthreads();

  const int wave = t >> 6, lane = t & 63;
  for (int node = wave; node < PP; node += 16) {
    float s1 = 0.f, s2 = 0.f, s3 = 0.f, s4 = 0.f;
    for (int f = lane * 4; f < FF; f += 256) {
      u16x4 hv = *(const u16x4*)&hs[node][f];
      u16x4 a1 = *(const u16x4*)(aV + f);
      u16x4 a2 = *(const u16x4*)(aV + FF + f);
#pragma unroll
      for (int j = 0; j < 4; j++) {
        float hf = bf2f(hv[j]);
        s1 += hf * bf2f(a1[j]);
        s2 += hf * bf2f(a2[j]);
      }
    }
    for (int f = FF + lane * 4; f < FF + LL; f += 256) {
      u16x4 hv = *(const u16x4*)&hs[node][f];
      u16x4 a3 = *(const u16x4*)(aL + (f - FF));
      u16x4 a4 = *(const u16x4*)(aL + LL + (f - FF));
#pragma unroll
      for (int j = 0; j < 4; j++) {
        float hf = bf2f(hv[j]);
        s3 += hf * bf2f(a3[j]);
        s4 += hf * bf2f(a4[j]);
      }
    }
#pragma unroll
    for (int o = 32; o > 0; o >>= 1) {
      s1 += __shfl_down(s1, o);
      s2 += __shfl_down(s2, o);
      s3 += __shfl_down(s3, o);
      s4 += __shfl_down(s4, o);
    }
    if (lane == 0) {
      esv[node] = s1; edv[node] = s2; esl[node] = s3; edl[node] = s4;
    }
  }
  __syncthreads();

  if (t < 2 * PP) {
    const int strm = t / PP, dd = t % PP;
    const float* es = strm ? esl : esv;
    const float ed = strm ? edl[dd] : edv[dd];
    float lg[PP];
    float m = -1e30f;
#pragma unroll
    for (int s = 0; s < PP; s++) {
      float e;
      if (s == dd) e = -1e30f;
      else {
        float v = es[s] + ed;
        e = (v > 0.f) ? v : 0.2f * v;
      }
      lg[s] = e;
      m = fmaxf(m, e);
    }
    float sum = 0.f;
#pragma unroll
    for (int s = 0; s < PP; s++) {
      lg[s] = expf(lg[s] - m);
      sum += lg[s];
    }
    float inv = 1.f / (sum + 1e-9f);
    float* al = strm ? alphaL : alphaV;
#pragma unroll
    for (int s = 0; s < PP; s++) al[s * PP + dd] = lg[s] * inv;
  }
  __syncthreads();

  for (int i = t; i < PP * CHROW; i += 1024) {
    int dd = i / CHROW, c = (i % CHROW) * 4;
    u16x4 ov;
    if (c >= FF + LL) {
      ov[0] = 0; ov[1] = 0; ov[2] = 0; ov[3] = 0;
    } else {
      const float* al = (c < FF) ? (alphaV + dd) : (alphaL + dd);
      float a0 = 0.f, a1 = 0.f, a2 = 0.f, a3 = 0.f;
#pragma unroll
      for (int s = 0; s < PP; s++) {
        float w = al[s * PP];
        u16x4 hv = *(const u16x4*)&hs[s][c];
        a0 += w * bf2f(hv[0]);
        a1 += w * bf2f(hv[1]);
        a2 += w * bf2f(hv[2]);
        a3 += w * bf2f(hv[3]);
      }
      u16x4 xv = *(const u16x4*)(xcat + base + (long)dd * DCAT + c);
      ov[0] = f2b(fmaxf(bf2f(xv[0]) + a0, 0.f));
      ov[1] = f2b(fmaxf(bf2f(xv[1]) + a1, 0.f));
      ov[2] = f2b(fmaxf(bf2f(xv[2]) + a2, 0.f));
      ov[3] = f2b(fmaxf(bf2f(xv[3]) + a3, 0.f));
    }
    *(u16x4*)(newcat + base + (long)dd * DCAT + c) = ov;
  }
}

// ---------------------------------------------------------------------------
// Combine, 8 edges/block (R8 version — 2432 blocks, high occupancy).
// ---------------------------------------------------------------------------
__global__ __launch_bounds__(256) void combine_kernel(
    const int* __restrict__ e_src, const int* __restrict__ e_dst,
    const int* __restrict__ r_eid, const void* __restrict__ spat_raw,
    const __hip_bfloat16* __restrict__ W1sp,
    const __hip_bfloat16* __restrict__ b1,
    const __hip_bfloat16* __restrict__ Yd, const __hip_bfloat16* __restrict__ Ys,
    __hip_bfloat16* __restrict__ hdn, const int* __restrict__ flag) {
  const int t = threadIdx.x;
  const int e0 = blockIdx.x * EPB;
  const int hd = t * 4;

  float w[SS][4];
#pragma unroll
  for (int k = 0; k < SS; k++) {
    u16x4 ww = *(const u16x4*)(W1sp + (long)k * HDIM + hd);
#pragma unroll
    for (int j = 0; j < 4; j++) w[k][j] = bf2f(ww[j]);
  }
  float bb[4];
  {
    u16x4 bv = *(const u16x4*)(b1 + hd);
#pragma unroll
    for (int j = 0; j < 4; j++) bb[j] = bf2f(bv[j]);
  }

  __shared__ int sh_s[EPB], sh_hx[EPB], sh_re[EPB];
  __shared__ float sh_sf[EPB][SS];
  if (t < EPB) {
    int re = r_eid[e0 + t];
    sh_re[t] = re;
    sh_s[t] = e_src[re];
    int d = e_dst[re];
    sh_hx[t] = (d / PP) * HH + (d % PP);
  }
  __syncthreads();
  if (t < EPB * SS) {
    int ee = t >> 4, k = t & 15;
    long idx = (long)sh_re[ee] * SS + k;
    sh_sf[ee][k] = flag[0]
                       ? ((const float*)spat_raw)[idx]
                       : __bfloat162float(((const __hip_bfloat16*)spat_raw)[idx]);
  }
  __syncthreads();

#pragma unroll
  for (int ee = 0; ee < EPB; ee++) {
    const int s = sh_s[ee];
    const int hx = sh_hx[ee];
    u16x4 yd = *(const u16x4*)(Yd + (long)hx * HDIM + hd);
    u16x4 ys = *(const u16x4*)(Ys + (long)s * HDIM + hd);
    float v[4];
#pragma unroll
    for (int j = 0; j < 4; j++) v[j] = bf2f(yd[j]) + bf2f(ys[j]) + bb[j];
#pragma unroll
    for (int k = 0; k < SS; k++) {
      float sfv = sh_sf[ee][k];
#pragma unroll
      for (int j = 0; j < 4; j++) v[j] += sfv * w[k][j];
    }
    u16x4 o;
#pragma unroll
    for (int j = 0; j < 4; j++) o[j] = f2b(fmaxf(v[j], 0.f));
    *(u16x4*)(hdn + (long)(e0 + ee) * HDIM + hd) = o;
  }
}

// ---------------------------------------------------------------------------
extern "C" void kernel_launch(void* const* d_in, const int* in_sizes, int n_in,
                              void* d_out, int out_size, void* d_ws,
                              size_t ws_size, hipStream_t stream) {
  const int* e_src = (const int*)d_in[11];
  const int* e_dst = (const int*)d_in[12];
  const int* r_eid = (const int*)d_in[13];
  (void)ws_size; (void)n_in; (void)in_sizes; (void)out_size;

  char* ws = (char*)d_ws;
  size_t off = 0;
  auto take = [&](size_t bytes) {
    char* p = ws + off;
    off += (bytes + 255) & ~(size_t)255;
    return p;
  };

  int* dflag = (int*)take(256);
  __hip_bfloat16* xcat   = (__hip_bfloat16*)take((size_t)NNODE * DCAT * 2);
  __hip_bfloat16* hcat   = (__hip_bfloat16*)take((size_t)NNODE * DCAT * 2);
  __hip_bfloat16* newcat = (__hip_bfloat16*)take((size_t)NNODE * DCAT * 2);
  __hip_bfloat16* cAv    = (__hip_bfloat16*)take((size_t)2 * FF * 2);
  __hip_bfloat16* cAl    = (__hip_bfloat16*)take((size_t)2 * LL * 2);
  __hip_bfloat16* cB1    = (__hip_bfloat16*)take((size_t)HDIM * 2);
  __hip_bfloat16* cB2    = (__hip_bfloat16*)take((size_t)CC * 2);
  __hip_bfloat16* cW1sp  = (__hip_bfloat16*)take((size_t)SS * HDIM * 2);
  __hip_bfloat16* WvT    = (__hip_bfloat16*)take((size_t)FF * FF * 2);
  __hip_bfloat16* WlT    = (__hip_bfloat16*)take((size_t)LL * LLP * 2);
  __hip_bfloat16* W1Td   = (__hip_bfloat16*)take((size_t)HDIM * DCAT * 2);
  __hip_bfloat16* W1Ts   = (__hip_bfloat16*)take((size_t)HDIM * DCAT * 2);
  __hip_bfloat16* W2T    = (__hip_bfloat16*)take((size_t)CC * HDIM * 2);
  __hip_bfloat16* Yd     = (__hip_bfloat16*)take((size_t)BB * HH * HDIM * 2);
  __hip_bfloat16* Ys     = (__hip_bfloat16*)take((size_t)NNODE * HDIM * 2);
  __hip_bfloat16* hdn    = (__hip_bfloat16*)take((size_t)NREAD * HDIM * 2);

  dim3 blk(256);

  // 1) ALL conversions + transposes (sniff inlined; block 0 persists dflag)
  prep_all<<<PREP_BLOCKS, blk, 0, stream>>>(
      d_in[0], d_in[1], d_in[3], d_in[4], d_in[5], d_in[6], d_in[7], d_in[8],
      d_in[9], d_in[10], xcat, cAv, cAl, cB1, cB2, cW1sp, WvT, WlT, W1Td, W1Ts,
      W2T, dflag);

  // 2) Projections (merged, staged dbuf GEMM, TK=64 + swizzle)
  {
    GDesc pv{xcat, WvT, hcat, nullptr,
             NNODE, FF, FF, DCAT, FF, DCAT, 0, 0, 0, 8, 80};
    GDesc pl{xcat + FF, WlT, hcat + FF, nullptr,
             NNODE, LL, LLP, DCAT, LLP, DCAT, 0, 0, 0, 3, 80};
    gemm_db<64, 128, 2, 2><<<dim3(8, 80, 2), blk, 0, stream>>>(pv, pl,
                                                               nullptr);
  }

  // 3) Fused logits + segment-softmax + message + residual relu
  attn_fused<<<BB, dim3(1024), 0, stream>>>(xcat, hcat, cAv, cAl, newcat);

  // 4) Concat-K projections (merged)
  {
    GDesc gys{newcat, W1Ts, Ys, nullptr,
              NNODE, HDIM, DCAT, DCAT, DCAT, HDIM, 0, 0, 0, 8, 80};
    GDesc gyd{newcat, W1Td, Yd, nullptr,
              BB * HH, HDIM, DCAT, DCAT, DCAT, HDIM, 1, 0, 0, 8, 16};
    gemm_db<64, 128, 2, 2><<<dim3(8, 80, 2), blk, 0, stream>>>(gys, gyd,
                                                               nullptr);
  }

  // 5) Combine + relu -> hdn (EPB=8, 2432 blocks — high occupancy)
  combine_kernel<<<NREAD / EPB, blk, 0, stream>>>(e_src, e_dst, r_eid, d_in[2],
                                                  cW1sp, cB1, Yd, Ys, hdn,
                                                  dflag);

  // 6) out = hdn @ W2 + b2 (32x128 tile, TK=64 staged GEMM; dtype per dflag)
  {
    GDesc go{hdn, W2T, d_out, cB2,
             NREAD, CC, HDIM, HDIM, HDIM, CC, 0, 0, 2, 1, 608};
    gemm_db<32, 128, 1, 4><<<dim3(1, 608, 1), blk, 0, stream>>>(go, go, dflag);
  }
}